// Round 2
// baseline (18285.226 us; speedup 1.0000x reference)
//
#include <hip/hip_runtime.h>

#define HID     128
#define NNODES  20000
#define NEDGES  640000
#define NSTEPS  10

// ---------------- encoders (node: KIN=16 skip first 2 feats; edge: KIN=3) ----------------
template<int KIN, int KSTART>
__global__ __launch_bounds__(128) void encoder_kernel(
    const float* __restrict__ in,
    const float* __restrict__ W1, const float* __restrict__ b1,
    const float* __restrict__ W2, const float* __restrict__ b2,
    const float* __restrict__ W3, const float* __restrict__ b3,
    float* __restrict__ out, int n)
{
    __shared__ float xs[16][(KIN < 4) ? 4 : KIN];
    __shared__ float h1[16][HID];
    __shared__ float h2[16][HID];
    const int t = threadIdx.x;
    const int base = blockIdx.x * 16;

    for (int i = t; i < 16 * KIN; i += 128) {
        int e = i / KIN, k = i % KIN;
        int g = base + e;
        xs[e][k] = (g < n) ? in[(size_t)g * KIN + k] : 0.f;
    }
    __syncthreads();

    {
        const float bb = b1[t];
        for (int e = 0; e < 16; ++e) {
            float acc = bb;
            #pragma unroll
            for (int k = KSTART; k < KIN; ++k) acc += xs[e][k] * W1[k * HID + t];
            h1[e][t] = fmaxf(acc, 0.f);
        }
    }
    __syncthreads();
    {
        const float bb = b2[t];
        for (int e = 0; e < 16; ++e) {
            float acc = bb;
            for (int k = 0; k < HID; ++k) acc += h1[e][k] * W2[k * HID + t];
            h2[e][t] = fmaxf(acc, 0.f);
        }
    }
    __syncthreads();
    {
        const float bb = b3[t];
        for (int e = 0; e < 16; ++e) {
            int g = base + e;
            if (g >= n) continue;
            float acc = bb;
            for (int k = 0; k < HID; ++k) acc += h2[e][k] * W3[k * HID + t];
            out[(size_t)g * HID + t] = acc;
        }
    }
}

// ---------------- fold edge-MLP layer 3 into each step's W1 lower block ----------------
// Wc[l] rows 0..127   = pW1[l] rows 0..127            (x_j part, unchanged)
// Wc[l] rows 128..255 = eW3 @ pW1[l] rows 128..255    (acts on h2e instead of edge_emb)
// g[l]                = pb1[l] + eb3 @ pW1[l] rows 128..255
__global__ __launch_bounds__(128) void fuse_kernel(
    const float* __restrict__ eW3, const float* __restrict__ eb3,
    const float* __restrict__ pW1, const float* __restrict__ pb1,
    float* __restrict__ Wc, float* __restrict__ g)
{
    const int l = blockIdx.x >> 3;
    const int s = blockIdx.x & 7;
    const int c = threadIdx.x;
    const float* W1l = pW1 + (size_t)l * 2 * HID * HID;
    float* Wcl = Wc + (size_t)l * 2 * HID * HID;

    for (int r = s * 16; r < s * 16 + 16; ++r)
        Wcl[r * HID + c] = W1l[r * HID + c];

    for (int m = s * 16; m < s * 16 + 16; ++m) {
        float a0 = 0.f, a1 = 0.f, a2 = 0.f, a3 = 0.f;
        for (int k = 0; k < HID; k += 4) {
            a0 += eW3[m * HID + k + 0] * W1l[(HID + k + 0) * HID + c];
            a1 += eW3[m * HID + k + 1] * W1l[(HID + k + 1) * HID + c];
            a2 += eW3[m * HID + k + 2] * W1l[(HID + k + 2) * HID + c];
            a3 += eW3[m * HID + k + 3] * W1l[(HID + k + 3) * HID + c];
        }
        Wcl[(HID + m) * HID + c] = (a0 + a1) + (a2 + a3);
    }

    if (s == 0) {
        float a = pb1[l * HID + c];
        for (int k = 0; k < HID; ++k)
            a += eb3[k] * W1l[(HID + k) * HID + c];
        g[l * HID + c] = a;
    }
}

// ---------------- in-degree (float atomics of 1.0 are exact) ----------------
__global__ void degree_kernel(const int* __restrict__ dst, float* __restrict__ cnt)
{
    int i = blockIdx.x * blockDim.x + threadIdx.x;
    if (i < NEDGES) {
        int d = dst[i];
        d = min(max(d, 0), NNODES - 1);
        atomicAdd(&cnt[d], 1.0f);
    }
}

// ---------------- per-step message MLP3 + scatter-add ----------------
// 32 edges/block, 256 threads. Per-thread tile: 4 edges x 4 contiguous cols.
// RECOMP: recompute edge-MLP h2e in-kernel (weights W1 = fused Wc_l, b1 = g_l).
// !RECOMP: read materialized edge_emb (weights W1 = pW1_l, b1 = pb1_l).
template<bool RECOMP>
__global__ __launch_bounds__(256) void msg_kernel(
    const float* __restrict__ node,
    const float* __restrict__ edge_emb,      // MAT path only
    const float* __restrict__ edge_attr,     // RECOMP only
    const float* __restrict__ eW1, const float* __restrict__ eb1,  // RECOMP only
    const float* __restrict__ eW2, const float* __restrict__ eb2,  // RECOMP only
    const int* __restrict__ src_idx,
    const int* __restrict__ dst_idx,
    const float* __restrict__ W1, const float* __restrict__ b1,   // [256,128]
    const float* __restrict__ W2, const float* __restrict__ b2,   // [128,128]
    const float* __restrict__ W3, const float* __restrict__ b3,   // [128,128]
    float* __restrict__ agg)
{
    __shared__ float X[32][256];
    __shared__ float H[32][HID];
    __shared__ int ssrc[32];
    __shared__ int sdst[32];
    __shared__ float ea_s[32][4];

    const int t = threadIdx.x;
    const int eb = blockIdx.x * 32;

    if (t < 32) {
        int s = src_idx[eb + t];
        ssrc[t] = min(max(s, 0), NNODES - 1);
    } else if (t < 64) {
        int d = dst_idx[eb + (t - 32)];
        sdst[t - 32] = min(max(d, 0), NNODES - 1);
    }
    __syncthreads();

    if (RECOMP) {
        // stage x_j (lower half of X) + raw edge_attr
        for (int i = t; i < 32 * 32; i += 256) {
            int e = i >> 5;
            int c = (i & 31) << 2;
            *(float4*)&X[e][c] = *(const float4*)&node[(size_t)ssrc[e] * HID + c];
        }
        for (int i = t; i < 32 * 3; i += 256)
            ea_s[i / 3][i % 3] = edge_attr[(size_t)(eb + i / 3) * 3 + (i % 3)];
    } else {
        // stage combined [x_j | edge_emb] rows, float4-vectorized
        for (int i = t; i < 32 * 64; i += 256) {
            int e = i >> 6;
            int c = (i & 63) << 2;
            float4 v;
            if (c < HID) v = *(const float4*)&node[(size_t)ssrc[e] * HID + c];
            else         v = *(const float4*)&edge_emb[(size_t)(eb + e) * HID + (c - HID)];
            *(float4*)&X[e][c] = v;
        }
    }
    __syncthreads();

    const int ct = t & 31;
    const int et = (t >> 5) << 2;   // edge base 0..28
    const int cb = ct << 2;         // col base 0..124
    float acc[4][4];

    if (RECOMP) {
        // h1e = relu(ea @ eW1 + eb1) -> H
        {
            const float4 bv = *(const float4*)&eb1[cb];
            #pragma unroll
            for (int j = 0; j < 4; ++j) { acc[j][0] = bv.x; acc[j][1] = bv.y; acc[j][2] = bv.z; acc[j][3] = bv.w; }
            #pragma unroll
            for (int k = 0; k < 3; ++k) {
                const float4 w = *(const float4*)&eW1[k * HID + cb];
                #pragma unroll
                for (int j = 0; j < 4; ++j) {
                    const float x = ea_s[et + j][k];
                    acc[j][0] += x * w.x; acc[j][1] += x * w.y; acc[j][2] += x * w.z; acc[j][3] += x * w.w;
                }
            }
            #pragma unroll
            for (int j = 0; j < 4; ++j) {
                float4 v = make_float4(fmaxf(acc[j][0], 0.f), fmaxf(acc[j][1], 0.f),
                                       fmaxf(acc[j][2], 0.f), fmaxf(acc[j][3], 0.f));
                *(float4*)&H[et + j][cb] = v;
            }
        }
        __syncthreads();
        // h2e = relu(h1e @ eW2 + eb2) -> X upper half
        {
            const float4 bv = *(const float4*)&eb2[cb];
            #pragma unroll
            for (int j = 0; j < 4; ++j) { acc[j][0] = bv.x; acc[j][1] = bv.y; acc[j][2] = bv.z; acc[j][3] = bv.w; }
            for (int k = 0; k < HID; ++k) {
                const float4 w = *(const float4*)&eW2[k * HID + cb];
                const float x0 = H[et + 0][k], x1 = H[et + 1][k], x2 = H[et + 2][k], x3 = H[et + 3][k];
                acc[0][0] += x0 * w.x; acc[0][1] += x0 * w.y; acc[0][2] += x0 * w.z; acc[0][3] += x0 * w.w;
                acc[1][0] += x1 * w.x; acc[1][1] += x1 * w.y; acc[1][2] += x1 * w.z; acc[1][3] += x1 * w.w;
                acc[2][0] += x2 * w.x; acc[2][1] += x2 * w.y; acc[2][2] += x2 * w.z; acc[2][3] += x2 * w.w;
                acc[3][0] += x3 * w.x; acc[3][1] += x3 * w.y; acc[3][2] += x3 * w.z; acc[3][3] += x3 * w.w;
            }
            #pragma unroll
            for (int j = 0; j < 4; ++j) {
                float4 v = make_float4(fmaxf(acc[j][0], 0.f), fmaxf(acc[j][1], 0.f),
                                       fmaxf(acc[j][2], 0.f), fmaxf(acc[j][3], 0.f));
                *(float4*)&X[et + j][HID + cb] = v;
            }
        }
        __syncthreads();
    }

    // ---- layer 1: K = 256 ----
    {
        const float4 bv = *(const float4*)&b1[cb];
        #pragma unroll
        for (int j = 0; j < 4; ++j) { acc[j][0] = bv.x; acc[j][1] = bv.y; acc[j][2] = bv.z; acc[j][3] = bv.w; }
        for (int k = 0; k < 256; ++k) {
            const float4 w = *(const float4*)&W1[k * HID + cb];
            const float x0 = X[et + 0][k], x1 = X[et + 1][k], x2 = X[et + 2][k], x3 = X[et + 3][k];
            acc[0][0] += x0 * w.x; acc[0][1] += x0 * w.y; acc[0][2] += x0 * w.z; acc[0][3] += x0 * w.w;
            acc[1][0] += x1 * w.x; acc[1][1] += x1 * w.y; acc[1][2] += x1 * w.z; acc[1][3] += x1 * w.w;
            acc[2][0] += x2 * w.x; acc[2][1] += x2 * w.y; acc[2][2] += x2 * w.z; acc[2][3] += x2 * w.w;
            acc[3][0] += x3 * w.x; acc[3][1] += x3 * w.y; acc[3][2] += x3 * w.z; acc[3][3] += x3 * w.w;
        }
        __syncthreads();   // ensure X reads done before H overwrite (RECOMP read H earlier too)
        #pragma unroll
        for (int j = 0; j < 4; ++j) {
            float4 v = make_float4(fmaxf(acc[j][0], 0.f), fmaxf(acc[j][1], 0.f),
                                   fmaxf(acc[j][2], 0.f), fmaxf(acc[j][3], 0.f));
            *(float4*)&H[et + j][cb] = v;
        }
    }
    __syncthreads();

    // ---- layer 2: K = 128, h1 -> h2 (h2 stored in X's space, X is dead) ----
    float* Xf = &X[0][0];
    {
        const float4 bv = *(const float4*)&b2[cb];
        #pragma unroll
        for (int j = 0; j < 4; ++j) { acc[j][0] = bv.x; acc[j][1] = bv.y; acc[j][2] = bv.z; acc[j][3] = bv.w; }
        for (int k = 0; k < HID; ++k) {
            const float4 w = *(const float4*)&W2[k * HID + cb];
            const float x0 = H[et + 0][k], x1 = H[et + 1][k], x2 = H[et + 2][k], x3 = H[et + 3][k];
            acc[0][0] += x0 * w.x; acc[0][1] += x0 * w.y; acc[0][2] += x0 * w.z; acc[0][3] += x0 * w.w;
            acc[1][0] += x1 * w.x; acc[1][1] += x1 * w.y; acc[1][2] += x1 * w.z; acc[1][3] += x1 * w.w;
            acc[2][0] += x2 * w.x; acc[2][1] += x2 * w.y; acc[2][2] += x2 * w.z; acc[2][3] += x2 * w.w;
            acc[3][0] += x3 * w.x; acc[3][1] += x3 * w.y; acc[3][2] += x3 * w.z; acc[3][3] += x3 * w.w;
        }
        #pragma unroll
        for (int j = 0; j < 4; ++j) {
            float4 v = make_float4(fmaxf(acc[j][0], 0.f), fmaxf(acc[j][1], 0.f),
                                   fmaxf(acc[j][2], 0.f), fmaxf(acc[j][3], 0.f));
            *(float4*)&Xf[(et + j) * HID + cb] = v;
        }
    }
    __syncthreads();

    // ---- layer 3: K = 128, h2 -> msg, scatter atomicAdd ----
    {
        const float4 bv = *(const float4*)&b3[cb];
        #pragma unroll
        for (int j = 0; j < 4; ++j) { acc[j][0] = bv.x; acc[j][1] = bv.y; acc[j][2] = bv.z; acc[j][3] = bv.w; }
        for (int k = 0; k < HID; ++k) {
            const float4 w = *(const float4*)&W3[k * HID + cb];
            const float x0 = Xf[(et + 0) * HID + k], x1 = Xf[(et + 1) * HID + k];
            const float x2 = Xf[(et + 2) * HID + k], x3 = Xf[(et + 3) * HID + k];
            acc[0][0] += x0 * w.x; acc[0][1] += x0 * w.y; acc[0][2] += x0 * w.z; acc[0][3] += x0 * w.w;
            acc[1][0] += x1 * w.x; acc[1][1] += x1 * w.y; acc[1][2] += x1 * w.z; acc[1][3] += x1 * w.w;
            acc[2][0] += x2 * w.x; acc[2][1] += x2 * w.y; acc[2][2] += x2 * w.z; acc[2][3] += x2 * w.w;
            acc[3][0] += x3 * w.x; acc[3][1] += x3 * w.y; acc[3][2] += x3 * w.z; acc[3][3] += x3 * w.w;
        }
        #pragma unroll
        for (int j = 0; j < 4; ++j) {
            const int d = sdst[et + j];
            float* ap = &agg[(size_t)d * HID + cb];
            atomicAdd(ap + 0, acc[j][0]);
            atomicAdd(ap + 1, acc[j][1]);
            atomicAdd(ap + 2, acc[j][2]);
            atomicAdd(ap + 3, acc[j][3]);
        }
    }
}

// ---------------- residual update: node += agg / max(cnt,1); re-zero agg ----------------
__global__ void update_kernel(float* __restrict__ node, float* __restrict__ agg,
                              const float* __restrict__ cnt)
{
    int i = blockIdx.x * blockDim.x + threadIdx.x;
    if (i < NNODES * HID) {
        int n = i >> 7;
        node[i] += agg[i] / fmaxf(cnt[n], 1.0f);
        agg[i] = 0.f;
    }
}

// ---------------- decoder: 128->128->128->2 ----------------
__global__ __launch_bounds__(128) void decoder_kernel(
    const float* __restrict__ node,
    const float* __restrict__ W1, const float* __restrict__ b1,
    const float* __restrict__ W2, const float* __restrict__ b2,
    const float* __restrict__ W3, const float* __restrict__ b3,   // [128,2]
    float* __restrict__ out)
{
    __shared__ float xs[16][HID];
    __shared__ float h1[16][HID];
    __shared__ float h2[16][HID];
    const int t = threadIdx.x;
    const int base = blockIdx.x * 16;

    for (int i = t; i < 16 * 32; i += 128) {
        int e = i >> 5, c = (i & 31) << 2;
        *(float4*)&xs[e][c] = *(const float4*)&node[(size_t)(base + e) * HID + c];
    }
    __syncthreads();
    {
        const float bb = b1[t];
        for (int e = 0; e < 16; ++e) {
            float acc = bb;
            for (int k = 0; k < HID; ++k) acc += xs[e][k] * W1[k * HID + t];
            h1[e][t] = fmaxf(acc, 0.f);
        }
    }
    __syncthreads();
    {
        const float bb = b2[t];
        for (int e = 0; e < 16; ++e) {
            float acc = bb;
            for (int k = 0; k < HID; ++k) acc += h1[e][k] * W2[k * HID + t];
            h2[e][t] = fmaxf(acc, 0.f);
        }
    }
    __syncthreads();
    if (t < 32) {
        const int e = t >> 1, o = t & 1;
        float acc = b3[o];
        for (int k = 0; k < HID; ++k) acc += h2[e][k] * W3[k * 2 + o];
        out[(size_t)(base + e) * 2 + o] = acc;
    }
}

extern "C" void kernel_launch(void* const* d_in, const int* in_sizes, int n_in,
                              void* d_out, int out_size, void* d_ws, size_t ws_size,
                              hipStream_t stream)
{
    const float* x         = (const float*)d_in[0];
    const float* edge_attr = (const float*)d_in[1];
    const float* nW1 = (const float*)d_in[2];  const float* nb1 = (const float*)d_in[3];
    const float* nW2 = (const float*)d_in[4];  const float* nb2 = (const float*)d_in[5];
    const float* nW3 = (const float*)d_in[6];  const float* nb3 = (const float*)d_in[7];
    const float* eW1 = (const float*)d_in[8];  const float* eb1 = (const float*)d_in[9];
    const float* eW2 = (const float*)d_in[10]; const float* eb2 = (const float*)d_in[11];
    const float* eW3 = (const float*)d_in[12]; const float* eb3 = (const float*)d_in[13];
    const float* pW1 = (const float*)d_in[14]; const float* pb1 = (const float*)d_in[15];
    const float* pW2 = (const float*)d_in[16]; const float* pb2 = (const float*)d_in[17];
    const float* pW3 = (const float*)d_in[18]; const float* pb3 = (const float*)d_in[19];
    const float* dW1 = (const float*)d_in[20]; const float* db1 = (const float*)d_in[21];
    const float* dW2 = (const float*)d_in[22]; const float* db2 = (const float*)d_in[23];
    const float* dW3 = (const float*)d_in[24]; const float* db3 = (const float*)d_in[25];
    const int* ei  = (const int*)d_in[26];
    const int* src = ei;
    const int* dst = ei + NEDGES;

    // workspace layout (bytes)
    char* ws = (char*)d_ws;
    float* node     = (float*)(ws);                  // 10,240,000
    float* agg      = (float*)(ws + 10240000);       // 10,240,000
    float* cnt      = (float*)(ws + 20480000);       //     80,000
    float* Wc       = (float*)(ws + 20560000);       //  1,310,720 (RECOMP)
    float* gb       = (float*)(ws + 21870720);       //      5,120 (RECOMP)
    float* edge_emb = (float*)(ws + 21875840);       // 327,680,000 (MAT only)
    const size_t NEED_MAT = 21875840ull + 327680000ull;

    const bool mat = (ws_size >= NEED_MAT);

    encoder_kernel<16, 2><<<NNODES / 16, 128, 0, stream>>>(
        x, nW1, nb1, nW2, nb2, nW3, nb3, node, NNODES);

    if (mat) {
        encoder_kernel<3, 0><<<NEDGES / 16, 128, 0, stream>>>(
            edge_attr, eW1, eb1, eW2, eb2, eW3, eb3, edge_emb, NEDGES);
    } else {
        fuse_kernel<<<NSTEPS * 8, 128, 0, stream>>>(eW3, eb3, pW1, pb1, Wc, gb);
    }

    // zero agg + cnt in one shot (contiguous)
    hipMemsetAsync(ws + 10240000, 0, 10240000 + 80000, stream);
    degree_kernel<<<(NEDGES + 255) / 256, 256, 0, stream>>>(dst, cnt);

    for (int l = 0; l < NSTEPS; ++l) {
        if (mat) {
            msg_kernel<false><<<NEDGES / 32, 256, 0, stream>>>(
                node, edge_emb, nullptr, nullptr, nullptr, nullptr, nullptr,
                src, dst,
                pW1 + (size_t)l * 2 * HID * HID, pb1 + l * HID,
                pW2 + (size_t)l * HID * HID,     pb2 + l * HID,
                pW3 + (size_t)l * HID * HID,     pb3 + l * HID,
                agg);
        } else {
            msg_kernel<true><<<NEDGES / 32, 256, 0, stream>>>(
                node, nullptr, edge_attr, eW1, eb1, eW2, eb2,
                src, dst,
                Wc + (size_t)l * 2 * HID * HID,  gb + l * HID,
                pW2 + (size_t)l * HID * HID,     pb2 + l * HID,
                pW3 + (size_t)l * HID * HID,     pb3 + l * HID,
                agg);
        }
        update_kernel<<<(NNODES * HID) / 256, 256, 0, stream>>>(node, agg, cnt);
    }

    decoder_kernel<<<NNODES / 16, 128, 0, stream>>>(
        node, dW1, db1, dW2, db2, dW3, db3, (float*)d_out);
}

// Round 3
// 18266.777 us; speedup vs baseline: 1.0010x; 1.0010x over previous
//
#include <hip/hip_runtime.h>

#define HID     128
#define NNODES  20000
#define NEDGES  640000
#define NSTEPS  10

typedef __attribute__((ext_vector_type(8)))  short short8;
typedef __attribute__((ext_vector_type(16))) float f32x16;

union Frag { short8 s; uint4 q; uint u[4]; };
union Acc  { f32x16 v; float f[16]; };

// element-packed hi|lo: u32 = bf16_trunc(x)<<... (top16) | bf16_trunc(x - hi)>>16
static __device__ inline uint pack_hl(float x) {
    uint hx = __float_as_uint(x) & 0xFFFF0000u;
    float lof = x - __uint_as_float(hx);
    return hx | (__float_as_uint(lof) >> 16);
}

// ---------------- node encoder (KIN=16, skip first 2 feats) ----------------
template<int KIN, int KSTART>
__global__ __launch_bounds__(128) void encoder_kernel(
    const float* __restrict__ in,
    const float* __restrict__ W1, const float* __restrict__ b1,
    const float* __restrict__ W2, const float* __restrict__ b2,
    const float* __restrict__ W3, const float* __restrict__ b3,
    float* __restrict__ out, int n)
{
    __shared__ float xs[16][(KIN < 4) ? 4 : KIN];
    __shared__ float h1[16][HID];
    __shared__ float h2[16][HID];
    const int t = threadIdx.x;
    const int base = blockIdx.x * 16;

    for (int i = t; i < 16 * KIN; i += 128) {
        int e = i / KIN, k = i % KIN;
        int g = base + e;
        xs[e][k] = (g < n) ? in[(size_t)g * KIN + k] : 0.f;
    }
    __syncthreads();
    {
        const float bb = b1[t];
        for (int e = 0; e < 16; ++e) {
            float acc = bb;
            #pragma unroll
            for (int k = KSTART; k < KIN; ++k) acc += xs[e][k] * W1[k * HID + t];
            h1[e][t] = fmaxf(acc, 0.f);
        }
    }
    __syncthreads();
    {
        const float bb = b2[t];
        for (int e = 0; e < 16; ++e) {
            float acc = bb;
            for (int k = 0; k < HID; ++k) acc += h1[e][k] * W2[k * HID + t];
            h2[e][t] = fmaxf(acc, 0.f);
        }
    }
    __syncthreads();
    {
        const float bb = b3[t];
        for (int e = 0; e < 16; ++e) {
            int g = base + e;
            if (g >= n) continue;
            float acc = bb;
            for (int k = 0; k < HID; ++k) acc += h2[e][k] * W3[k * HID + t];
            out[(size_t)g * HID + t] = acc;
        }
    }
}

// ---------------- edge encoder writing B-frag layout directly ----------------
// emb_frag u32 layout: (((eb*8 + ks)*2 + pl)*64 + lane)*4 + word
//   eb = e/32, lane = (e%32) + 32*((c%16)/8), ks = c/16, word = (c&7)>>1
__global__ __launch_bounds__(128) void edge_encoder_frag(
    const float* __restrict__ in,
    const float* __restrict__ W1, const float* __restrict__ b1,
    const float* __restrict__ W2, const float* __restrict__ b2,
    const float* __restrict__ W3, const float* __restrict__ b3,
    uint* __restrict__ emb_frag)
{
    __shared__ float xs[16][4];
    __shared__ float h1[16][HID];
    __shared__ float h2[16][HID];
    __shared__ float h3[16][HID];
    const int t = threadIdx.x;
    const int base = blockIdx.x * 16;

    for (int i = t; i < 16 * 3; i += 128)
        xs[i / 3][i % 3] = in[(size_t)(base + i / 3) * 3 + (i % 3)];
    __syncthreads();
    {
        const float bb = b1[t];
        for (int e = 0; e < 16; ++e) {
            float acc = bb;
            #pragma unroll
            for (int k = 0; k < 3; ++k) acc += xs[e][k] * W1[k * HID + t];
            h1[e][t] = fmaxf(acc, 0.f);
        }
    }
    __syncthreads();
    {
        const float bb = b2[t];
        for (int e = 0; e < 16; ++e) {
            float acc = bb;
            for (int k = 0; k < HID; ++k) acc += h1[e][k] * W2[k * HID + t];
            h2[e][t] = fmaxf(acc, 0.f);
        }
    }
    __syncthreads();
    {
        const float bb = b3[t];
        for (int e = 0; e < 16; ++e) {
            float acc = bb;
            for (int k = 0; k < HID; ++k) acc += h2[e][k] * W3[k * HID + t];
            h3[e][t] = acc;
        }
    }
    __syncthreads();

    // pack pairs (c0 even) into hi/lo planes of frag layout
    for (int i = t; i < 16 * 64; i += 128) {
        const int e = i >> 6;
        const int c0 = (i & 63) << 1;
        const int ge = base + e;
        const float x0 = h3[e][c0], x1 = h3[e][c0 + 1];
        const uint b0h = __float_as_uint(x0) & 0xFFFF0000u;
        const uint b1h = __float_as_uint(x1) & 0xFFFF0000u;
        const float l0 = x0 - __uint_as_float(b0h);
        const float l1 = x1 - __uint_as_float(b1h);
        const uint whi = b1h | (b0h >> 16);
        const uint wlo = (__float_as_uint(l1) & 0xFFFF0000u) | (__float_as_uint(l0) >> 16);
        const int eb = ge >> 5;
        const int lane = (ge & 31) + 32 * ((c0 & 15) >> 3);
        const int ks = c0 >> 4;
        const int word = (c0 & 7) >> 1;
        const size_t bi = ((((size_t)eb * 8 + ks) * 2) * 64 + lane) * 4 + word;
        emb_frag[bi] = whi;            // pl = 0
        emb_frag[bi + 64 * 4] = wlo;   // pl = 1
    }
}

// ---------------- weight repack: A = W^T frags, hi/lo planes ----------------
// per step (uint4 units): L1 [16ks][4rb][2pl][64] = 8192, L2 @8192 (4096), L3 @12288
__global__ __launch_bounds__(256) void wprep_kernel(
    const float* __restrict__ pW1, const float* __restrict__ pW2,
    const float* __restrict__ pW3, uint4* __restrict__ wfrag)
{
    const int gid = blockIdx.x * 256 + threadIdx.x;   // 163840 total
    const int sid = gid / 16384;
    const int r   = gid % 16384;
    int layer, rr;
    if (r < 8192)       { layer = 0; rr = r; }
    else if (r < 12288) { layer = 1; rr = r - 8192; }
    else                { layer = 2; rr = r - 12288; }
    const int ks  = rr >> 9;
    const int rem = rr & 511;
    const int rb  = rem >> 7;
    const int pl  = (rem >> 6) & 1;
    const int l   = rem & 63;
    const int c   = rb * 32 + (l & 31);
    const int k0  = ks * 16 + 8 * (l >> 5);

    const float* Wsrc = (layer == 0) ? pW1 + (size_t)sid * 2 * HID * HID
                      : (layer == 1) ? pW2 + (size_t)sid * HID * HID
                                     : pW3 + (size_t)sid * HID * HID;
    uint b16[8];
    #pragma unroll
    for (int j = 0; j < 8; ++j) {
        float x = Wsrc[(size_t)(k0 + j) * HID + c];
        uint hx = __float_as_uint(x) & 0xFFFF0000u;
        if (pl == 0) b16[j] = hx >> 16;
        else {
            float lof = x - __uint_as_float(hx);
            b16[j] = __float_as_uint(lof) >> 16;
        }
    }
    uint4 o;
    o.x = b16[0] | (b16[1] << 16);
    o.y = b16[2] | (b16[3] << 16);
    o.z = b16[4] | (b16[5] << 16);
    o.w = b16[6] | (b16[7] << 16);
    wfrag[gid] = o;
}

// ---------------- in-degree ----------------
__global__ void degree_kernel(const int* __restrict__ dst, float* __restrict__ cnt)
{
    int i = blockIdx.x * blockDim.x + threadIdx.x;
    if (i < NEDGES) {
        int d = dst[i];
        d = min(max(d, 0), NNODES - 1);
        atomicAdd(&cnt[d], 1.0f);
    }
}

// ---------------- MFMA message kernel: 64 edges/block, 4 waves (col-specialized) ----------------
#define MFMA(a, b, c) __builtin_amdgcn_mfma_f32_32x32x16_bf16((a), (b), (c), 0, 0, 0)

static __device__ inline void bbuild(const uint* __restrict__ rowp, int xorv, int k0,
                                     Frag& bh, Frag& bl)
{
    const int s0 = k0 >> 2;
    const uint4 r0 = *(const uint4*)&rowp[((s0 ^ xorv) << 2)];
    const uint4 r1 = *(const uint4*)&rowp[(((s0 + 1) ^ xorv) << 2)];
    bh.u[0] = (r0.y & 0xFFFF0000u) | (r0.x >> 16);
    bl.u[0] = (r0.y << 16)         | (r0.x & 0xFFFFu);
    bh.u[1] = (r0.w & 0xFFFF0000u) | (r0.z >> 16);
    bl.u[1] = (r0.w << 16)         | (r0.z & 0xFFFFu);
    bh.u[2] = (r1.y & 0xFFFF0000u) | (r1.x >> 16);
    bl.u[2] = (r1.y << 16)         | (r1.x & 0xFFFFu);
    bh.u[3] = (r1.w & 0xFFFF0000u) | (r1.z >> 16);
    bl.u[3] = (r1.w << 16)         | (r1.z & 0xFFFFu);
}

__global__ __launch_bounds__(256) void msg_mfma(
    const float* __restrict__ node,
    const uint4* __restrict__ emb_frag,
    const uint4* __restrict__ wfrag,          // this step's base
    const int*  __restrict__ src_idx,
    const int*  __restrict__ dst_idx,
    const float* __restrict__ b1, const float* __restrict__ b2,
    const float* __restrict__ b3,
    float* __restrict__ agg)
{
    __shared__ uint Xin[64 * 128];
    __shared__ uint Hb[64 * 128];
    __shared__ int ssrc[64];
    __shared__ int sdst[64];

    const int t = threadIdx.x;
    const int w = t >> 6;          // wave id -> col block (32 cols)
    const int l = t & 63;
    const int l31 = l & 31;
    const int g = l >> 5;
    const int eb0 = blockIdx.x * 64;

    if (t < 64) {
        int s = src_idx[eb0 + t];
        ssrc[t] = min(max(s, 0), NNODES - 1);
    } else if (t < 128) {
        int d = dst_idx[eb0 + (t - 64)];
        sdst[t - 64] = min(max(d, 0), NNODES - 1);
    }
    __syncthreads();

    // stage x_j as packed hi|lo u32, XOR-swizzled 16B slots
    #pragma unroll
    for (int i = t; i < 64 * 32; i += 256) {
        const int e = i >> 5;
        const int s = i & 31;
        const float4 v = *(const float4*)&node[(size_t)ssrc[e] * HID + s * 4];
        uint4 p;
        p.x = pack_hl(v.x); p.y = pack_hl(v.y); p.z = pack_hl(v.z); p.w = pack_hl(v.w);
        *(uint4*)&Xin[e * 128 + ((s ^ (e & 31)) << 2)] = p;
    }
    __syncthreads();

    Acc aA0, aB0, aA1, aB1;   // eb0: (AhBh+AlBh), (AhBl); eb1 same
    #pragma unroll
    for (int i = 0; i < 16; ++i) { aA0.f[i] = 0.f; aB0.f[i] = 0.f; aA1.f[i] = 0.f; aB1.f[i] = 0.f; }

    const int e0 = l31;        // eb = 0
    const int e1 = 32 + l31;   // eb = 1

    // ---------------- layer 1: K = 256 (k<128 from Xin, k>=128 from emb_frag) ----------------
    #pragma unroll 4
    for (int ks = 0; ks < 16; ++ks) {
        Frag ah, al;
        ah.q = wfrag[((ks * 4 + w) * 2 + 0) * 64 + l];
        al.q = wfrag[((ks * 4 + w) * 2 + 1) * 64 + l];
        Frag bh0, bl0, bh1, bl1;
        if (ks < 8) {
            const int k0 = ks * 16 + 8 * g;
            bbuild(&Xin[e0 * 128], e0 & 31, k0, bh0, bl0);
            bbuild(&Xin[e1 * 128], e1 & 31, k0, bh1, bl1);
        } else {
            const size_t base0 = (((size_t)(eb0 >> 5) + 0) * 8 + (ks - 8)) * 2;
            const size_t base1 = (((size_t)(eb0 >> 5) + 1) * 8 + (ks - 8)) * 2;
            bh0.q = emb_frag[(base0 + 0) * 64 + l];
            bl0.q = emb_frag[(base0 + 1) * 64 + l];
            bh1.q = emb_frag[(base1 + 0) * 64 + l];
            bl1.q = emb_frag[(base1 + 1) * 64 + l];
        }
        aA0.v = MFMA(ah.s, bh0.s, aA0.v);
        aA1.v = MFMA(ah.s, bh1.s, aA1.v);
        aA0.v = MFMA(al.s, bh0.s, aA0.v);
        aA1.v = MFMA(al.s, bh1.s, aA1.v);
        aB0.v = MFMA(ah.s, bl0.s, aB0.v);
        aB1.v = MFMA(ah.s, bl1.s, aB1.v);
    }
    // epilogue -> Hb (bias + relu)
    #pragma unroll
    for (int q = 0; q < 4; ++q) {
        const int c0 = w * 32 + q * 8 + 4 * g;
        const float4 bv = *(const float4*)&b1[c0];
        uint4 p0, p1;
        p0.x = pack_hl(fmaxf(aA0.f[q*4+0] + aB0.f[q*4+0] + bv.x, 0.f));
        p0.y = pack_hl(fmaxf(aA0.f[q*4+1] + aB0.f[q*4+1] + bv.y, 0.f));
        p0.z = pack_hl(fmaxf(aA0.f[q*4+2] + aB0.f[q*4+2] + bv.z, 0.f));
        p0.w = pack_hl(fmaxf(aA0.f[q*4+3] + aB0.f[q*4+3] + bv.w, 0.f));
        p1.x = pack_hl(fmaxf(aA1.f[q*4+0] + aB1.f[q*4+0] + bv.x, 0.f));
        p1.y = pack_hl(fmaxf(aA1.f[q*4+1] + aB1.f[q*4+1] + bv.y, 0.f));
        p1.z = pack_hl(fmaxf(aA1.f[q*4+2] + aB1.f[q*4+2] + bv.z, 0.f));
        p1.w = pack_hl(fmaxf(aA1.f[q*4+3] + aB1.f[q*4+3] + bv.w, 0.f));
        const int sl = c0 >> 2;
        *(uint4*)&Hb[e0 * 128 + ((sl ^ (e0 & 31)) << 2)] = p0;
        *(uint4*)&Hb[e1 * 128 + ((sl ^ (e1 & 31)) << 2)] = p1;
    }
    __syncthreads();

    // ---------------- layer 2: K = 128 (Hb -> Xin) ----------------
    #pragma unroll
    for (int i = 0; i < 16; ++i) { aA0.f[i] = 0.f; aB0.f[i] = 0.f; aA1.f[i] = 0.f; aB1.f[i] = 0.f; }
    const uint4* wf2 = wfrag + 8192;
    #pragma unroll 4
    for (int ks = 0; ks < 8; ++ks) {
        Frag ah, al;
        ah.q = wf2[((ks * 4 + w) * 2 + 0) * 64 + l];
        al.q = wf2[((ks * 4 + w) * 2 + 1) * 64 + l];
        Frag bh0, bl0, bh1, bl1;
        const int k0 = ks * 16 + 8 * g;
        bbuild(&Hb[e0 * 128], e0 & 31, k0, bh0, bl0);
        bbuild(&Hb[e1 * 128], e1 & 31, k0, bh1, bl1);
        aA0.v = MFMA(ah.s, bh0.s, aA0.v);
        aA1.v = MFMA(ah.s, bh1.s, aA1.v);
        aA0.v = MFMA(al.s, bh0.s, aA0.v);
        aA1.v = MFMA(al.s, bh1.s, aA1.v);
        aB0.v = MFMA(ah.s, bl0.s, aB0.v);
        aB1.v = MFMA(ah.s, bl1.s, aB1.v);
    }
    #pragma unroll
    for (int q = 0; q < 4; ++q) {
        const int c0 = w * 32 + q * 8 + 4 * g;
        const float4 bv = *(const float4*)&b2[c0];
        uint4 p0, p1;
        p0.x = pack_hl(fmaxf(aA0.f[q*4+0] + aB0.f[q*4+0] + bv.x, 0.f));
        p0.y = pack_hl(fmaxf(aA0.f[q*4+1] + aB0.f[q*4+1] + bv.y, 0.f));
        p0.z = pack_hl(fmaxf(aA0.f[q*4+2] + aB0.f[q*4+2] + bv.z, 0.f));
        p0.w = pack_hl(fmaxf(aA0.f[q*4+3] + aB0.f[q*4+3] + bv.w, 0.f));
        p1.x = pack_hl(fmaxf(aA1.f[q*4+0] + aB1.f[q*4+0] + bv.x, 0.f));
        p1.y = pack_hl(fmaxf(aA1.f[q*4+1] + aB1.f[q*4+1] + bv.y, 0.f));
        p1.z = pack_hl(fmaxf(aA1.f[q*4+2] + aB1.f[q*4+2] + bv.z, 0.f));
        p1.w = pack_hl(fmaxf(aA1.f[q*4+3] + aB1.f[q*4+3] + bv.w, 0.f));
        const int sl = c0 >> 2;
        *(uint4*)&Xin[e0 * 128 + ((sl ^ (e0 & 31)) << 2)] = p0;
        *(uint4*)&Xin[e1 * 128 + ((sl ^ (e1 & 31)) << 2)] = p1;
    }
    __syncthreads();

    // ---------------- layer 3: K = 128 (Xin = h2) -> scatter atomics ----------------
    #pragma unroll
    for (int i = 0; i < 16; ++i) { aA0.f[i] = 0.f; aB0.f[i] = 0.f; aA1.f[i] = 0.f; aB1.f[i] = 0.f; }
    const uint4* wf3 = wfrag + 12288;
    #pragma unroll 4
    for (int ks = 0; ks < 8; ++ks) {
        Frag ah, al;
        ah.q = wf3[((ks * 4 + w) * 2 + 0) * 64 + l];
        al.q = wf3[((ks * 4 + w) * 2 + 1) * 64 + l];
        Frag bh0, bl0, bh1, bl1;
        const int k0 = ks * 16 + 8 * g;
        bbuild(&Xin[e0 * 128], e0 & 31, k0, bh0, bl0);
        bbuild(&Xin[e1 * 128], e1 & 31, k0, bh1, bl1);
        aA0.v = MFMA(ah.s, bh0.s, aA0.v);
        aA1.v = MFMA(ah.s, bh1.s, aA1.v);
        aA0.v = MFMA(al.s, bh0.s, aA0.v);
        aA1.v = MFMA(al.s, bh1.s, aA1.v);
        aB0.v = MFMA(ah.s, bl0.s, aB0.v);
        aB1.v = MFMA(ah.s, bl1.s, aB1.v);
    }
    const int d0 = sdst[e0];
    const int d1 = sdst[e1];
    #pragma unroll
    for (int q = 0; q < 4; ++q) {
        const int c0 = w * 32 + q * 8 + 4 * g;
        const float4 bv = *(const float4*)&b3[c0];
        float* a0 = &agg[(size_t)d0 * HID + c0];
        float* a1 = &agg[(size_t)d1 * HID + c0];
        atomicAdd(a0 + 0, aA0.f[q*4+0] + aB0.f[q*4+0] + bv.x);
        atomicAdd(a0 + 1, aA0.f[q*4+1] + aB0.f[q*4+1] + bv.y);
        atomicAdd(a0 + 2, aA0.f[q*4+2] + aB0.f[q*4+2] + bv.z);
        atomicAdd(a0 + 3, aA0.f[q*4+3] + aB0.f[q*4+3] + bv.w);
        atomicAdd(a1 + 0, aA1.f[q*4+0] + aB1.f[q*4+0] + bv.x);
        atomicAdd(a1 + 1, aA1.f[q*4+1] + aB1.f[q*4+1] + bv.y);
        atomicAdd(a1 + 2, aA1.f[q*4+2] + aB1.f[q*4+2] + bv.z);
        atomicAdd(a1 + 3, aA1.f[q*4+3] + aB1.f[q*4+3] + bv.w);
    }
}

// ---------------- residual update: node += agg / max(cnt,1); re-zero agg ----------------
__global__ void update_kernel(float* __restrict__ node, float* __restrict__ agg,
                              const float* __restrict__ cnt)
{
    int i = blockIdx.x * blockDim.x + threadIdx.x;
    if (i < NNODES * HID) {
        int n = i >> 7;
        node[i] += agg[i] / fmaxf(cnt[n], 1.0f);
        agg[i] = 0.f;
    }
}

// ---------------- decoder: 128->128->128->2 ----------------
__global__ __launch_bounds__(128) void decoder_kernel(
    const float* __restrict__ node,
    const float* __restrict__ W1, const float* __restrict__ b1,
    const float* __restrict__ W2, const float* __restrict__ b2,
    const float* __restrict__ W3, const float* __restrict__ b3,
    float* __restrict__ out)
{
    __shared__ float xs[16][HID];
    __shared__ float h1[16][HID];
    __shared__ float h2[16][HID];
    const int t = threadIdx.x;
    const int base = blockIdx.x * 16;

    for (int i = t; i < 16 * 32; i += 128) {
        int e = i >> 5, c = (i & 31) << 2;
        *(float4*)&xs[e][c] = *(const float4*)&node[(size_t)(base + e) * HID + c];
    }
    __syncthreads();
    {
        const float bb = b1[t];
        for (int e = 0; e < 16; ++e) {
            float acc = bb;
            for (int k = 0; k < HID; ++k) acc += xs[e][k] * W1[k * HID + t];
            h1[e][t] = fmaxf(acc, 0.f);
        }
    }
    __syncthreads();
    {
        const float bb = b2[t];
        for (int e = 0; e < 16; ++e) {
            float acc = bb;
            for (int k = 0; k < HID; ++k) acc += h1[e][k] * W2[k * HID + t];
            h2[e][t] = fmaxf(acc, 0.f);
        }
    }
    __syncthreads();
    if (t < 32) {
        const int e = t >> 1, o = t & 1;
        float acc = b3[o];
        for (int k = 0; k < HID; ++k) acc += h2[e][k] * W3[k * 2 + o];
        out[(size_t)(base + e) * 2 + o] = acc;
    }
}

// ================= fallback (RECOMP fp32 path, from round 2) =================
__global__ __launch_bounds__(128) void fuse_kernel(
    const float* __restrict__ eW3, const float* __restrict__ eb3,
    const float* __restrict__ pW1, const float* __restrict__ pb1,
    float* __restrict__ Wc, float* __restrict__ g)
{
    const int l = blockIdx.x >> 3;
    const int s = blockIdx.x & 7;
    const int c = threadIdx.x;
    const float* W1l = pW1 + (size_t)l * 2 * HID * HID;
    float* Wcl = Wc + (size_t)l * 2 * HID * HID;

    for (int r = s * 16; r < s * 16 + 16; ++r)
        Wcl[r * HID + c] = W1l[r * HID + c];

    for (int m = s * 16; m < s * 16 + 16; ++m) {
        float a0 = 0.f, a1 = 0.f, a2 = 0.f, a3 = 0.f;
        for (int k = 0; k < HID; k += 4) {
            a0 += eW3[m * HID + k + 0] * W1l[(HID + k + 0) * HID + c];
            a1 += eW3[m * HID + k + 1] * W1l[(HID + k + 1) * HID + c];
            a2 += eW3[m * HID + k + 2] * W1l[(HID + k + 2) * HID + c];
            a3 += eW3[m * HID + k + 3] * W1l[(HID + k + 3) * HID + c];
        }
        Wcl[(HID + m) * HID + c] = (a0 + a1) + (a2 + a3);
    }
    if (s == 0) {
        float a = pb1[l * HID + c];
        for (int k = 0; k < HID; ++k)
            a += eb3[k] * W1l[(HID + k) * HID + c];
        g[l * HID + c] = a;
    }
}

__global__ __launch_bounds__(256) void msg_recomp(
    const float* __restrict__ node,
    const float* __restrict__ edge_attr,
    const float* __restrict__ eW1, const float* __restrict__ eb1,
    const float* __restrict__ eW2, const float* __restrict__ eb2,
    const int* __restrict__ src_idx, const int* __restrict__ dst_idx,
    const float* __restrict__ W1, const float* __restrict__ b1,
    const float* __restrict__ W2, const float* __restrict__ b2,
    const float* __restrict__ W3, const float* __restrict__ b3,
    float* __restrict__ agg)
{
    __shared__ float X[32][256];
    __shared__ float H[32][HID];
    __shared__ int ssrc[32];
    __shared__ int sdst[32];
    __shared__ float ea_s[32][4];

    const int t = threadIdx.x;
    const int eb = blockIdx.x * 32;

    if (t < 32) { int s = src_idx[eb + t]; ssrc[t] = min(max(s, 0), NNODES - 1); }
    else if (t < 64) { int d = dst_idx[eb + (t - 32)]; sdst[t - 32] = min(max(d, 0), NNODES - 1); }
    __syncthreads();

    for (int i = t; i < 32 * 32; i += 256) {
        int e = i >> 5; int c = (i & 31) << 2;
        *(float4*)&X[e][c] = *(const float4*)&node[(size_t)ssrc[e] * HID + c];
    }
    for (int i = t; i < 32 * 3; i += 256)
        ea_s[i / 3][i % 3] = edge_attr[(size_t)(eb + i / 3) * 3 + (i % 3)];
    __syncthreads();

    const int ct = t & 31;
    const int et = (t >> 5) << 2;
    const int cb = ct << 2;
    float acc[4][4];

    { // edge h1
        const float4 bv = *(const float4*)&eb1[cb];
        #pragma unroll
        for (int j = 0; j < 4; ++j) { acc[j][0] = bv.x; acc[j][1] = bv.y; acc[j][2] = bv.z; acc[j][3] = bv.w; }
        #pragma unroll
        for (int k = 0; k < 3; ++k) {
            const float4 wv = *(const float4*)&eW1[k * HID + cb];
            #pragma unroll
            for (int j = 0; j < 4; ++j) {
                const float x = ea_s[et + j][k];
                acc[j][0] += x * wv.x; acc[j][1] += x * wv.y; acc[j][2] += x * wv.z; acc[j][3] += x * wv.w;
            }
        }
        #pragma unroll
        for (int j = 0; j < 4; ++j)
            *(float4*)&H[et + j][cb] = make_float4(fmaxf(acc[j][0],0.f), fmaxf(acc[j][1],0.f), fmaxf(acc[j][2],0.f), fmaxf(acc[j][3],0.f));
    }
    __syncthreads();
    { // edge h2 -> X upper
        const float4 bv = *(const float4*)&eb2[cb];
        #pragma unroll
        for (int j = 0; j < 4; ++j) { acc[j][0] = bv.x; acc[j][1] = bv.y; acc[j][2] = bv.z; acc[j][3] = bv.w; }
        for (int k = 0; k < HID; ++k) {
            const float4 wv = *(const float4*)&eW2[k * HID + cb];
            const float x0 = H[et+0][k], x1 = H[et+1][k], x2 = H[et+2][k], x3 = H[et+3][k];
            acc[0][0]+=x0*wv.x; acc[0][1]+=x0*wv.y; acc[0][2]+=x0*wv.z; acc[0][3]+=x0*wv.w;
            acc[1][0]+=x1*wv.x; acc[1][1]+=x1*wv.y; acc[1][2]+=x1*wv.z; acc[1][3]+=x1*wv.w;
            acc[2][0]+=x2*wv.x; acc[2][1]+=x2*wv.y; acc[2][2]+=x2*wv.z; acc[2][3]+=x2*wv.w;
            acc[3][0]+=x3*wv.x; acc[3][1]+=x3*wv.y; acc[3][2]+=x3*wv.z; acc[3][3]+=x3*wv.w;
        }
        #pragma unroll
        for (int j = 0; j < 4; ++j)
            *(float4*)&X[et + j][HID + cb] = make_float4(fmaxf(acc[j][0],0.f), fmaxf(acc[j][1],0.f), fmaxf(acc[j][2],0.f), fmaxf(acc[j][3],0.f));
    }
    __syncthreads();
    { // layer1 K=256
        const float4 bv = *(const float4*)&b1[cb];
        #pragma unroll
        for (int j = 0; j < 4; ++j) { acc[j][0] = bv.x; acc[j][1] = bv.y; acc[j][2] = bv.z; acc[j][3] = bv.w; }
        for (int k = 0; k < 256; ++k) {
            const float4 wv = *(const float4*)&W1[k * HID + cb];
            const float x0 = X[et+0][k], x1 = X[et+1][k], x2 = X[et+2][k], x3 = X[et+3][k];
            acc[0][0]+=x0*wv.x; acc[0][1]+=x0*wv.y; acc[0][2]+=x0*wv.z; acc[0][3]+=x0*wv.w;
            acc[1][0]+=x1*wv.x; acc[1][1]+=x1*wv.y; acc[1][2]+=x1*wv.z; acc[1][3]+=x1*wv.w;
            acc[2][0]+=x2*wv.x; acc[2][1]+=x2*wv.y; acc[2][2]+=x2*wv.z; acc[2][3]+=x2*wv.w;
            acc[3][0]+=x3*wv.x; acc[3][1]+=x3*wv.y; acc[3][2]+=x3*wv.z; acc[3][3]+=x3*wv.w;
        }
        __syncthreads();
        #pragma unroll
        for (int j = 0; j < 4; ++j)
            *(float4*)&H[et + j][cb] = make_float4(fmaxf(acc[j][0],0.f), fmaxf(acc[j][1],0.f), fmaxf(acc[j][2],0.f), fmaxf(acc[j][3],0.f));
    }
    __syncthreads();
    float* Xf = &X[0][0];
    { // layer2
        const float4 bv = *(const float4*)&b2[cb];
        #pragma unroll
        for (int j = 0; j < 4; ++j) { acc[j][0] = bv.x; acc[j][1] = bv.y; acc[j][2] = bv.z; acc[j][3] = bv.w; }
        for (int k = 0; k < HID; ++k) {
            const float4 wv = *(const float4*)&W2[k * HID + cb];
            const float x0 = H[et+0][k], x1 = H[et+1][k], x2 = H[et+2][k], x3 = H[et+3][k];
            acc[0][0]+=x0*wv.x; acc[0][1]+=x0*wv.y; acc[0][2]+=x0*wv.z; acc[0][3]+=x0*wv.w;
            acc[1][0]+=x1*wv.x; acc[1][1]+=x1*wv.y; acc[1][2]+=x1*wv.z; acc[1][3]+=x1*wv.w;
            acc[2][0]+=x2*wv.x; acc[2][1]+=x2*wv.y; acc[2][2]+=x2*wv.z; acc[2][3]+=x2*wv.w;
            acc[3][0]+=x3*wv.x; acc[3][1]+=x3*wv.y; acc[3][2]+=x3*wv.z; acc[3][3]+=x3*wv.w;
        }
        #pragma unroll
        for (int j = 0; j < 4; ++j)
            *(float4*)&Xf[(et + j) * HID + cb] = make_float4(fmaxf(acc[j][0],0.f), fmaxf(acc[j][1],0.f), fmaxf(acc[j][2],0.f), fmaxf(acc[j][3],0.f));
    }
    __syncthreads();
    { // layer3 + scatter
        const float4 bv = *(const float4*)&b3[cb];
        #pragma unroll
        for (int j = 0; j < 4; ++j) { acc[j][0] = bv.x; acc[j][1] = bv.y; acc[j][2] = bv.z; acc[j][3] = bv.w; }
        for (int k = 0; k < HID; ++k) {
            const float4 wv = *(const float4*)&W3[k * HID + cb];
            const float x0 = Xf[(et+0)*HID+k], x1 = Xf[(et+1)*HID+k];
            const float x2 = Xf[(et+2)*HID+k], x3 = Xf[(et+3)*HID+k];
            acc[0][0]+=x0*wv.x; acc[0][1]+=x0*wv.y; acc[0][2]+=x0*wv.z; acc[0][3]+=x0*wv.w;
            acc[1][0]+=x1*wv.x; acc[1][1]+=x1*wv.y; acc[1][2]+=x1*wv.z; acc[1][3]+=x1*wv.w;
            acc[2][0]+=x2*wv.x; acc[2][1]+=x2*wv.y; acc[2][2]+=x2*wv.z; acc[2][3]+=x2*wv.w;
            acc[3][0]+=x3*wv.x; acc[3][1]+=x3*wv.y; acc[3][2]+=x3*wv.z; acc[3][3]+=x3*wv.w;
        }
        #pragma unroll
        for (int j = 0; j < 4; ++j) {
            const int d = sdst[et + j];
            float* ap = &agg[(size_t)d * HID + cb];
            atomicAdd(ap + 0, acc[j][0]);
            atomicAdd(ap + 1, acc[j][1]);
            atomicAdd(ap + 2, acc[j][2]);
            atomicAdd(ap + 3, acc[j][3]);
        }
    }
}

extern "C" void kernel_launch(void* const* d_in, const int* in_sizes, int n_in,
                              void* d_out, int out_size, void* d_ws, size_t ws_size,
                              hipStream_t stream)
{
    const float* x         = (const float*)d_in[0];
    const float* edge_attr = (const float*)d_in[1];
    const float* nW1 = (const float*)d_in[2];  const float* nb1 = (const float*)d_in[3];
    const float* nW2 = (const float*)d_in[4];  const float* nb2 = (const float*)d_in[5];
    const float* nW3 = (const float*)d_in[6];  const float* nb3 = (const float*)d_in[7];
    const float* eW1 = (const float*)d_in[8];  const float* eb1 = (const float*)d_in[9];
    const float* eW2 = (const float*)d_in[10]; const float* eb2 = (const float*)d_in[11];
    const float* eW3 = (const float*)d_in[12]; const float* eb3 = (const float*)d_in[13];
    const float* pW1 = (const float*)d_in[14]; const float* pb1 = (const float*)d_in[15];
    const float* pW2 = (const float*)d_in[16]; const float* pb2 = (const float*)d_in[17];
    const float* pW3 = (const float*)d_in[18]; const float* pb3 = (const float*)d_in[19];
    const float* dW1 = (const float*)d_in[20]; const float* db1 = (const float*)d_in[21];
    const float* dW2 = (const float*)d_in[22]; const float* db2 = (const float*)d_in[23];
    const float* dW3 = (const float*)d_in[24]; const float* db3 = (const float*)d_in[25];
    const int* ei  = (const int*)d_in[26];
    const int* src = ei;
    const int* dst = ei + NEDGES;

    // workspace layout (bytes)
    char* ws = (char*)d_ws;
    float* node     = (float*)(ws);                  // 10,240,000
    float* agg      = (float*)(ws + 10240000);       // 10,240,000
    float* cnt      = (float*)(ws + 20480000);       //     80,000
    uint4* wfrag    = (uint4*)(ws + 20560000);       //  2,621,440
    uint*  emb_frag = (uint*)(ws + 23181440);        // 327,680,000
    const size_t NEED_MFMA = 23181440ull + 327680000ull;

    // fallback layout
    float* Wc = (float*)(ws + 20560000);             // 1,310,720
    float* gb = (float*)(ws + 21870720);             //     5,120

    const bool mfma_path = (ws_size >= NEED_MFMA);

    encoder_kernel<16, 2><<<NNODES / 16, 128, 0, stream>>>(
        x, nW1, nb1, nW2, nb2, nW3, nb3, node, NNODES);

    hipMemsetAsync(ws + 10240000, 0, 10240000 + 80000, stream);
    degree_kernel<<<(NEDGES + 255) / 256, 256, 0, stream>>>(dst, cnt);

    if (mfma_path) {
        edge_encoder_frag<<<NEDGES / 16, 128, 0, stream>>>(
            edge_attr, eW1, eb1, eW2, eb2, eW3, eb3, emb_frag);
        wprep_kernel<<<640, 256, 0, stream>>>(pW1, pW2, pW3, wfrag);

        for (int l = 0; l < NSTEPS; ++l) {
            msg_mfma<<<NEDGES / 64, 256, 0, stream>>>(
                node, (const uint4*)emb_frag, wfrag + (size_t)l * 16384,
                src, dst,
                pb1 + l * HID, pb2 + l * HID, pb3 + l * HID, agg);
            update_kernel<<<(NNODES * HID) / 256, 256, 0, stream>>>(node, agg, cnt);
        }
    } else {
        fuse_kernel<<<NSTEPS * 8, 128, 0, stream>>>(eW3, eb3, pW1, pb1, Wc, gb);
        for (int l = 0; l < NSTEPS; ++l) {
            msg_recomp<<<NEDGES / 32, 256, 0, stream>>>(
                node, edge_attr, eW1, eb1, eW2, eb2, src, dst,
                Wc + (size_t)l * 2 * HID * HID,  gb + l * HID,
                pW2 + (size_t)l * HID * HID,     pb2 + l * HID,
                pW3 + (size_t)l * HID * HID,     pb3 + l * HID,
                agg);
            update_kernel<<<(NNODES * HID) / 256, 256, 0, stream>>>(node, agg, cnt);
        }
    }

    decoder_kernel<<<NNODES / 16, 128, 0, stream>>>(
        node, dW1, db1, dW2, db2, dW3, db3, (float*)d_out);
}